// Round 5
// baseline (497.196 us; speedup 1.0000x reference)
//
#include <hip/hip_runtime.h>
#include <hip/hip_bf16.h>
#include <stdint.h>

// Problem constants
#define MB_  8
#define NQ_  256
#define NKV_ 4096
#define E_   1024
#define H_   16
#define D_   64

typedef __bf16 bf16x8 __attribute__((ext_vector_type(8)));
typedef float  f32x4  __attribute__((ext_vector_type(4)));
typedef unsigned short u16;
typedef unsigned short u16x8 __attribute__((ext_vector_type(8)));

#define MFMA16(a,b,c) __builtin_amdgcn_mfma_f32_16x16x32_bf16((a),(b),(c),0,0,0)

__device__ __forceinline__ u16 f2bf(float f) {
  uint32_t u = __float_as_uint(f);
  u += 0x7fffu + ((u >> 16) & 1u);   // RNE (no NaNs in this workload)
  return (u16)(u >> 16);
}

__device__ __forceinline__ void gload_lds16(const void* g, void* l) {
  __builtin_amdgcn_global_load_lds(
      (const __attribute__((address_space(1))) void*)g,
      (__attribute__((address_space(3))) void*)l, 16, 0, 0);
}

// Stage a 128-row x 128-byte bf16 tile (row stride ldbytes) into LDS.
// Swizzle applied via the GLOBAL source address (rule #21): LDS byte (row,cb)
// holds source (row, cb ^ ((row&7)<<4)).
__device__ __forceinline__ void stage_tile(const char* __restrict__ g, int ldbytes,
                                           char* lds, int t) {
  int srcCB = (((t & 7) ^ ((t >> 3) & 7)) << 4);
  const char* gp = g + (long long)(t >> 3) * ldbytes + srcCB;
  char* lp = lds + ((t >> 6) << 10);
#pragma unroll
  for (int i = 0; i < 4; ++i) {
    gload_lds16(gp + (long long)(32 * i) * ldbytes, lp + i * 4096);
  }
}

// Stage a 128-row x 64-col FLOAT32 tile (row stride ldf floats) into LDS as
// bf16 with the same swizzled layout as stage_tile. Reg-stage: float4 load ->
// RNE convert -> 8B ds_write at swizzled byte-col. Write aliasing <= 2-way
// (free, m136); loads are 256B-contiguous per 16-lane group.
__device__ __forceinline__ void stage_tile_f32(const float* __restrict__ g, int ldf,
                                               char* lds, int t) {
#pragma unroll
  for (int i = 0; i < 8; ++i) {
    int flat = t + i * 256;          // 0..2047
    int row = flat >> 4;             // 0..127
    int c4 = flat & 15;              // float4 col index (f32 cols c4*4..+3)
    float4 v = *(const float4*)(g + (long long)row * ldf + c4 * 4);
    uint32_t lo = (uint32_t)f2bf(v.x) | ((uint32_t)f2bf(v.y) << 16);
    uint32_t hi = (uint32_t)f2bf(v.z) | ((uint32_t)f2bf(v.w) << 16);
    int cb = (c4 * 8) ^ ((row & 7) << 4);
    *(uint2*)(lds + row * 128 + cb) = make_uint2(lo, hi);
  }
}

// Read one MFMA fragment (8 contiguous bf16 at (row r, col-byte cb)) with swizzle.
__device__ __forceinline__ bf16x8 read_frag(const char* lds, int r, int cb) {
  return *(const bf16x8*)(lds + r * 128 + (cb ^ ((r & 7) << 4)));
}

// ---------------------------------------------------------------------------
// Generic NT GEMM: C[M x N] = A[M x K] @ Bt[N x K]^T, f32 acc.
// ASRC 0: A is bf16 (global_load_lds staging). ASRC 1: A is f32 (reg-stage +
//         convert; fuses the f32->bf16 pass into the GEMM).
// MODE 0: store bf16 C.
// MODE 2: split-K x4 -> f32 partials; z encodes (ks = z>>3, m = z&7), each
//         split covers K=1024. Combined by pv_combine (fixed order).
// 128x128 tile, BK=64, 256 threads (2x2 waves, each 64x64).
// XCD-aware bijective swizzle (m157): (gridDim.x*gridDim.y) % 8 == 0 holds
// for all launches here.
// ---------------------------------------------------------------------------
template <int MODE, int ASRC>
__global__ __launch_bounds__(256, 2) void gemm_nt(
    const void* __restrict__ Av, const u16* __restrict__ Bt, void* __restrict__ Cv,
    int lda, int ldb, int ldc, int K,
    long long sA, long long sB, long long sC) {
  __shared__ __align__(16) char smA[16384];
  __shared__ __align__(16) char smB[16384];
  int zz = blockIdx.z;
  int b = (MODE == 2) ? (zz & 7) : zz;
  int ks = (MODE == 2) ? (zz >> 3) : 0;
  long long koff = (long long)ks * 1024;

  // XCD swizzle: keep same-A-panel blocks on one XCD
  unsigned nwg = gridDim.x * gridDim.y;
  unsigned orig = blockIdx.y * gridDim.x + blockIdx.x;
  unsigned cpx = nwg >> 3;
  unsigned swz = (orig & 7) * cpx + (orig >> 3);
  unsigned bx = swz % gridDim.x, by = swz / gridDim.x;

  const char* Ap;      // ASRC 0: byte pointer (bf16)
  const float* Apf;    // ASRC 1: f32 pointer
  if (ASRC == 0)
    Ap = (const char*)((const u16*)Av + (long long)b * sA + (long long)by * 128 * lda + koff);
  else
    Apf = (const float*)Av + (long long)b * sA + (long long)by * 128 * lda + koff;
  const char* Bp = (const char*)(Bt + (long long)b * sB + (long long)bx * 128 * ldb + koff);

  int t = threadIdx.x, lane = t & 63;
  int wm = t >> 7, wn = (t >> 6) & 1;
  int rl = lane & 15, kq = lane >> 4;

  f32x4 acc[4][4];
#pragma unroll
  for (int i = 0; i < 4; ++i)
#pragma unroll
    for (int j = 0; j < 4; ++j) acc[i][j] = (f32x4){0.f, 0.f, 0.f, 0.f};

  int ldab = lda * 2, ldbb = ldb * 2;
  for (int k0 = 0; k0 < K; k0 += 64) {
    if (ASRC == 0)
      stage_tile(Ap + k0 * 2, ldab, smA, t);
    else
      stage_tile_f32(Apf + k0, lda, smA, t);
    stage_tile(Bp + k0 * 2, ldbb, smB, t);
    __syncthreads();
    bf16x8 af[4][2], bf[4][2];
#pragma unroll
    for (int f = 0; f < 4; ++f)
#pragma unroll
      for (int ksl = 0; ksl < 2; ++ksl) {
        af[f][ksl] = read_frag(smA, wm * 64 + f * 16 + rl, ksl * 64 + kq * 16);
        bf[f][ksl] = read_frag(smB, wn * 64 + f * 16 + rl, ksl * 64 + kq * 16);
      }
#pragma unroll
    for (int fm = 0; fm < 4; ++fm)
#pragma unroll
      for (int fn = 0; fn < 4; ++fn) {
        acc[fm][fn] = MFMA16(af[fm][0], bf[fn][0], acc[fm][fn]);
        acc[fm][fn] = MFMA16(af[fm][1], bf[fn][1], acc[fm][fn]);
      }
    __syncthreads();
  }

  // Epilogue. C/D layout: col = lane&15, row = (lane>>4)*4 + reg  [m89-verified]
#pragma unroll
  for (int fm = 0; fm < 4; ++fm)
#pragma unroll
    for (int fn = 0; fn < 4; ++fn)
#pragma unroll
      for (int j = 0; j < 4; ++j) {
        int row = by * 128 + wm * 64 + fm * 16 + kq * 4 + j;
        int col = bx * 128 + wn * 64 + fn * 16 + rl;
        if (MODE == 0) {
          ((u16*)Cv)[(long long)b * sC + (long long)row * ldc + col] = f2bf(acc[fm][fn][j]);
        } else {
          ((float*)Cv)[((long long)(ks * 8 + b)) * sC + (long long)row * ldc + col] =
              acc[fm][fn][j];
        }
      }
}

// ---------------------------------------------------------------------------
// PV split-K combine: out = xq + sum of 4 partials. Fixed order, vectorized.
// 524288 float4's -> 2048 blocks x 256.
// ---------------------------------------------------------------------------
__global__ void pv_combine(const float* __restrict__ part, const float* __restrict__ xq,
                           float* __restrict__ out) {
  int i = blockIdx.x * 256 + threadIdx.x;
  float4 s = ((const float4*)xq)[i];
#pragma unroll
  for (int k = 0; k < 4; ++k) {
    float4 p = ((const float4*)(part + (long long)k * 2097152))[i];
    s.x += p.x; s.y += p.y; s.z += p.z; s.w += p.w;
  }
  ((float4*)out)[i] = s;
}

// ---------------------------------------------------------------------------
// Pass 1: tile-structured row sums of exp(S), no max shift (scores ~N(0,1)
// by construction; f32 sumexp has ~30 orders of headroom).
// K is the MFMA A-operand -> C rows = keys, C cols = q. Row-sum over keys is
// a per-thread register reduction + 2 shfl_xor over kq lane-groups.
// Per-wm partials -> 64 slices, combined by stats_combine (deterministic).
// grid = (kt=32, qt=2, z=16: m=z>>1, hhalf=z&1), block = 256 (2x2 waves).
// ---------------------------------------------------------------------------
__global__ __launch_bounds__(256, 4) void attn_stats(
    const u16* __restrict__ qg, const u16* __restrict__ kg,
    float* __restrict__ lstP) {
  __shared__ __align__(16) char smQ[16384];
  __shared__ __align__(16) char smK[16384];
  int kt = blockIdx.x, qt = blockIdx.y;
  int m = blockIdx.z >> 1, hh = blockIdx.z & 1;
  int t = threadIdx.x, lane = t & 63;
  int wm = t >> 7, wn = (t >> 6) & 1;
  int rl = lane & 15, kq = lane >> 4;

  const char* qbase = (const char*)(qg + ((long long)(m * NQ_ + qt * 128)) * 1024);
  const char* kbase = (const char*)(kg + ((long long)(m * NKV_ + kt * 128)) * 1024);

  for (int hi = 0; hi < 8; ++hi) {
    int h = hh * 8 + hi;
    stage_tile(qbase + h * 128, 2048, smQ, t);
    stage_tile(kbase + h * 128, 2048, smK, t);
    __syncthreads();
    bf16x8 kf[4][2], qf[4][2];
#pragma unroll
    for (int f = 0; f < 4; ++f)
#pragma unroll
      for (int ksl = 0; ksl < 2; ++ksl) {
        kf[f][ksl] = read_frag(smK, wm * 64 + f * 16 + rl, ksl * 64 + kq * 16);
        qf[f][ksl] = read_frag(smQ, wn * 64 + f * 16 + rl, ksl * 64 + kq * 16);
      }
    float rs[4] = {0.f, 0.f, 0.f, 0.f};
#pragma unroll
    for (int fm = 0; fm < 4; ++fm)
#pragma unroll
      for (int fn = 0; fn < 4; ++fn) {
        f32x4 sc = (f32x4){0.f, 0.f, 0.f, 0.f};
        sc = MFMA16(kf[fm][0], qf[fn][0], sc);
        sc = MFMA16(kf[fm][1], qf[fn][1], sc);
        rs[fn] += (__expf(sc[0]) + __expf(sc[1])) + (__expf(sc[2]) + __expf(sc[3]));
      }
#pragma unroll
    for (int fn = 0; fn < 4; ++fn) {
      float v = rs[fn];
      v += __shfl_xor(v, 16);
      v += __shfl_xor(v, 32);
      if (lane < 16) {
        int q = qt * 128 + wn * 64 + fn * 16 + rl;
        lstP[(long long)(kt * 2 + wm) * 32768 + ((m * H_ + h) << 8) + q] = v;
      }
    }
    __syncthreads();
  }
}

// ---------------------------------------------------------------------------
// Merge the 64 (kt x wm) partial sums. Fixed order -> deterministic.
// ---------------------------------------------------------------------------
__global__ void stats_combine(const float* __restrict__ lp, float* __restrict__ lst) {
  int i = blockIdx.x * 256 + threadIdx.x;
  float s = 0.f;
#pragma unroll
  for (int k = 0; k < 64; ++k) s += lp[(long long)k * 32768 + i];
  lst[i] = s;
}

// ---------------------------------------------------------------------------
// Pass 2: Pbar[m,q,k] = sum_h (hw[h]/l[m,h,q]) * exp(s_h), bf16 out (no max).
// grid = (kt=32, qt=2, m=8), block = 256.
// ---------------------------------------------------------------------------
__global__ __launch_bounds__(256, 2) void pbar_kernel(
    const u16* __restrict__ qg, const u16* __restrict__ kg,
    const float* __restrict__ lstat,
    const float* __restrict__ rawhw, u16* __restrict__ Pbar) {
  __shared__ __align__(16) char smQ[16384];
  __shared__ __align__(16) char smK[16384];
  __shared__ float scf[2048];
  int kt = blockIdx.x, qt = blockIdx.y, m = blockIdx.z;
  int q0 = qt * 128, k0 = kt * 128;
  int t = threadIdx.x, lane = t & 63;
  int wm = t >> 7, wn = (t >> 6) & 1;
  int rl = lane & 15, kq = lane >> 4;

  // head-weight softmax (redundant per thread; 16 elements, L1-served)
  float hm = -1e30f;
  for (int i = 0; i < H_; ++i) hm = fmaxf(hm, rawhw[i]);
  float hs = 0.f, hw[H_];
  for (int i = 0; i < H_; ++i) { hw[i] = __expf(rawhw[i] - hm); hs += hw[i]; }
  float hinv = 1.f / hs;
  for (int idx = t; idx < 2048; idx += 256) {
    int h = idx >> 7, r = idx & 127;
    scf[idx] = hw[h] * hinv / lstat[((m * H_ + h) << 8) + q0 + r];
  }

  f32x4 pacc[4][4];
#pragma unroll
  for (int i = 0; i < 4; ++i)
#pragma unroll
    for (int j = 0; j < 4; ++j) pacc[i][j] = (f32x4){0.f, 0.f, 0.f, 0.f};

  const char* qbase = (const char*)(qg + ((long long)(m * NQ_ + q0)) * 1024);
  const char* kbase = (const char*)(kg + ((long long)(m * NKV_ + k0)) * 1024);

  for (int h = 0; h < H_; ++h) {
    stage_tile(qbase + h * 128, 2048, smQ, t);
    stage_tile(kbase + h * 128, 2048, smK, t);
    __syncthreads();  // also orders the scf writes above (first iter)
    bf16x8 af[4][2], bfr[4][2];
#pragma unroll
    for (int f = 0; f < 4; ++f)
#pragma unroll
      for (int ksl = 0; ksl < 2; ++ksl) {
        af[f][ksl] = read_frag(smQ, wm * 64 + f * 16 + rl, ksl * 64 + kq * 16);
        bfr[f][ksl] = read_frag(smK, wn * 64 + f * 16 + rl, ksl * 64 + kq * 16);
      }
#pragma unroll
    for (int fm = 0; fm < 4; ++fm) {
      int rbase = wm * 64 + fm * 16 + kq * 4;
      float cf0 = scf[(h << 7) + rbase + 0];
      float cf1 = scf[(h << 7) + rbase + 1];
      float cf2 = scf[(h << 7) + rbase + 2];
      float cf3 = scf[(h << 7) + rbase + 3];
#pragma unroll
      for (int fn = 0; fn < 4; ++fn) {
        f32x4 sc = (f32x4){0.f, 0.f, 0.f, 0.f};
        sc = MFMA16(af[fm][0], bfr[fn][0], sc);
        sc = MFMA16(af[fm][1], bfr[fn][1], sc);
        pacc[fm][fn][0] += cf0 * __expf(sc[0]);
        pacc[fm][fn][1] += cf1 * __expf(sc[1]);
        pacc[fm][fn][2] += cf2 * __expf(sc[2]);
        pacc[fm][fn][3] += cf3 * __expf(sc[3]);
      }
    }
    __syncthreads();
  }
#pragma unroll
  for (int fm = 0; fm < 4; ++fm)
#pragma unroll
    for (int fn = 0; fn < 4; ++fn)
#pragma unroll
      for (int j = 0; j < 4; ++j) {
        int row = q0 + wm * 64 + fm * 16 + kq * 4 + j;
        int col = k0 + wn * 64 + fn * 16 + rl;
        Pbar[(((long long)m * NQ_ + row) << 12) + col] = f2bf(pacc[fm][fn][j]);
      }
}

// ---------------------------------------------------------------------------
// Transposed f32 -> bf16 convert (out[c][r] = alpha * in[r][c]), batched.
// block (32,8), 32x32 tiles.
// ---------------------------------------------------------------------------
__global__ void tcvt(const float* __restrict__ in, u16* __restrict__ out,
                     int R, int C, long long sIn, long long sOut, float alpha) {
  __shared__ float tile[32][33];
  long long bIn = (long long)blockIdx.z * sIn;
  long long bOut = (long long)blockIdx.z * sOut;
  int c0 = blockIdx.x * 32, r0 = blockIdx.y * 32;
  int tx = threadIdx.x, ty = threadIdx.y;
#pragma unroll
  for (int i = 0; i < 32; i += 8)
    tile[ty + i][tx] = in[bIn + (long long)(r0 + ty + i) * C + c0 + tx];
  __syncthreads();
#pragma unroll
  for (int i = 0; i < 32; i += 8)
    out[bOut + (long long)(c0 + ty + i) * R + r0 + tx] = f2bf(alpha * tile[tx][ty + i]);
}

// ---------------------------------------------------------------------------
extern "C" void kernel_launch(void* const* d_in, const int* in_sizes, int n_in,
                              void* d_out, int out_size, void* d_ws, size_t ws_size,
                              hipStream_t stream) {
  const float* zq  = (const float*)d_in[0];
  const float* zkv = (const float*)d_in[1];
  const float* xq  = (const float*)d_in[2];
  const float* xkv = (const float*)d_in[3];
  const float* Wq  = (const float*)d_in[4];
  const float* Wk  = (const float*)d_in[5];
  const float* rhw = (const float*)d_in[6];
  float* out = (float*)d_out;

  // Workspace layout (bytes). Total need: ~204 MB (fits the round-1 budget).
  char* ws = (char*)d_ws;
  u16* WqT  = (u16*)(ws);                      //  2 MB  [1024][1024] (x0.125 folded)
  u16* WkT  = (u16*)(ws + (2ull << 20));       //  2 MB
  u16* qb   = (u16*)(ws + (8ull << 20));       //  4 MB  [2048][1024] (pre-scaled)
  u16* kb   = (u16*)(ws + (12ull << 20));      // 64 MB  [32768][1024]
  u16* xkvT = (u16*)(ws + (76ull << 20));      // 64 MB  [8][1024][4096]
  char* zr  = ws + (140ull << 20);             // 64 MB region:
  u16* Pbar = (u16*)zr;                        //   Pbar [8][256][4096] (16 MB)
  float* lst  = (float*)(zr + (18ull << 20));  //   final sumexp (128 KB)
  float* lstP = (float*)(zr + (20ull << 20));  //   partial sumexp [64][32768] (8 MB)
  float* pvP  = (float*)(zr + (28ull << 20));  //   PV split-K partials [4][8][256][1024] (32 MB)

  // 0. zq passthrough (output 0)
  hipMemcpyAsync(d_out, (const void*)zq, (size_t)MB_ * NQ_ * E_ * sizeof(float),
                 hipMemcpyDeviceToDevice, stream);

  // 1. weight / V transposes (f32 -> bf16)
  dim3 tb(32, 8);
  tcvt<<<dim3(32, 32, 1), tb, 0, stream>>>(Wq, WqT, 1024, 1024, 0, 0, 0.125f);  // fold SCALE
  tcvt<<<dim3(32, 32, 1), tb, 0, stream>>>(Wk, WkT, 1024, 1024, 0, 0, 1.0f);
  tcvt<<<dim3(32, 128, 8), tb, 0, stream>>>(xkv, xkvT, NKV_, E_,
                                            (long long)NKV_ * E_, (long long)NKV_ * E_, 1.0f);

  // 2. projections (NT GEMM, f32 A staged+converted in-kernel, bf16 out)
  gemm_nt<0, 1><<<dim3(8, 16, 1), 256, 0, stream>>>(zq, WqT, qb,
                                                    1024, 1024, 1024, 1024, 0, 0, 0);
  gemm_nt<0, 1><<<dim3(8, 256, 1), 256, 0, stream>>>(zkv, WkT, kb,
                                                     1024, 1024, 1024, 1024, 0, 0, 0);

  // 3. softmax denominators: tile-structured partial sums, then combine
  attn_stats<<<dim3(32, 2, 16), 256, 0, stream>>>(qb, kb, lstP);
  stats_combine<<<128, 256, 0, stream>>>(lstP, lst);

  // 4. head-collapsed probabilities
  pbar_kernel<<<dim3(32, 2, 8), 256, 0, stream>>>(qb, kb, lst, rhw, Pbar);

  // 5. PV split-K x4 -> f32 partials, then combine with residual
  gemm_nt<2, 0><<<dim3(8, 2, 32), 256, 0, stream>>>(Pbar, xkvT, pvP,
                                                    4096, 4096, 1024, 1024,
                                                    256LL * 4096, 1024LL * 4096,
                                                    256LL * 1024);
  pv_combine<<<2048, 256, 0, stream>>>(pvP, xq, out + (long long)MB_ * NQ_ * E_);
}

// Round 6
// 313.992 us; speedup vs baseline: 1.5835x; 1.5835x over previous
//
#include <hip/hip_runtime.h>
#include <hip/hip_bf16.h>
#include <stdint.h>

// Problem constants
#define MB_  8
#define NQ_  256
#define NKV_ 4096
#define E_   1024
#define H_   16
#define D_   64

typedef __bf16 bf16x8 __attribute__((ext_vector_type(8)));
typedef float  f32x4  __attribute__((ext_vector_type(4)));
typedef unsigned short u16;
typedef unsigned short u16x8 __attribute__((ext_vector_type(8)));

#define MFMA16(a,b,c) __builtin_amdgcn_mfma_f32_16x16x32_bf16((a),(b),(c),0,0,0)

__device__ __forceinline__ u16 f2bf(float f) {
  uint32_t u = __float_as_uint(f);
  u += 0x7fffu + ((u >> 16) & 1u);   // RNE (no NaNs in this workload)
  return (u16)(u >> 16);
}

__device__ __forceinline__ void gload_lds16(const void* g, void* l) {
  __builtin_amdgcn_global_load_lds(
      (const __attribute__((address_space(1))) void*)g,
      (__attribute__((address_space(3))) void*)l, 16, 0, 0);
}

// Stage a 128-row x 128-byte bf16 tile (row stride ldbytes) into LDS.
// Swizzle applied via the GLOBAL source address (rule #21): LDS byte (row,cb)
// holds source (row, cb ^ ((row&7)<<4)).
// NOTE (R5 post-mortem): reg-staged f32->bf16 fusion here regressed 3x
// (serialized load->wait->ds_write->barrier, no async overlap). Keep
// global_load_lds staging; do dtype converts in separate HBM-bound kernels.
__device__ __forceinline__ void stage_tile(const char* __restrict__ g, int ldbytes,
                                           char* lds, int t) {
  int srcCB = (((t & 7) ^ ((t >> 3) & 7)) << 4);
  const char* gp = g + (long long)(t >> 3) * ldbytes + srcCB;
  char* lp = lds + ((t >> 6) << 10);
#pragma unroll
  for (int i = 0; i < 4; ++i) {
    gload_lds16(gp + (long long)(32 * i) * ldbytes, lp + i * 4096);
  }
}

// Read one MFMA fragment (8 contiguous bf16 at (row r, col-byte cb)) with swizzle.
__device__ __forceinline__ bf16x8 read_frag(const char* lds, int r, int cb) {
  return *(const bf16x8*)(lds + r * 128 + (cb ^ ((r & 7) << 4)));
}

// ---------------------------------------------------------------------------
// Generic NT GEMM: C[M x N] = A[M x K] @ Bt[N x K]^T, bf16 in, f32 acc.
// MODE 0: store bf16 C.
// MODE 2: split-K x4 -> f32 partials; z encodes (ks = z>>3, m = z&7), each
//         split covers K=1024. Combined by pv_combine (fixed order).
// 128x128 tile, BK=64, 256 threads (2x2 waves, each 64x64).
// XCD-aware bijective swizzle (m157): (gridDim.x*gridDim.y) % 8 == 0 holds
// for all launches here.
// ---------------------------------------------------------------------------
template <int MODE>
__global__ __launch_bounds__(256, 2) void gemm_nt(
    const u16* __restrict__ A, const u16* __restrict__ Bt, void* __restrict__ Cv,
    int lda, int ldb, int ldc, int K,
    long long sA, long long sB, long long sC) {
  __shared__ __align__(16) char smA[16384];
  __shared__ __align__(16) char smB[16384];
  int zz = blockIdx.z;
  int b = (MODE == 2) ? (zz & 7) : zz;
  int ks = (MODE == 2) ? (zz >> 3) : 0;
  long long koff = (long long)ks * 1024;

  // XCD swizzle: keep same-A-panel blocks on one XCD
  unsigned nwg = gridDim.x * gridDim.y;
  unsigned orig = blockIdx.y * gridDim.x + blockIdx.x;
  unsigned cpx = nwg >> 3;
  unsigned swz = (orig & 7) * cpx + (orig >> 3);
  unsigned bx = swz % gridDim.x, by = swz / gridDim.x;

  const char* Ap = (const char*)(A + (long long)b * sA + (long long)by * 128 * lda + koff);
  const char* Bp = (const char*)(Bt + (long long)b * sB + (long long)bx * 128 * ldb + koff);

  int t = threadIdx.x, lane = t & 63;
  int wm = t >> 7, wn = (t >> 6) & 1;
  int rl = lane & 15, kq = lane >> 4;

  f32x4 acc[4][4];
#pragma unroll
  for (int i = 0; i < 4; ++i)
#pragma unroll
    for (int j = 0; j < 4; ++j) acc[i][j] = (f32x4){0.f, 0.f, 0.f, 0.f};

  int ldab = lda * 2, ldbb = ldb * 2;
  for (int k0 = 0; k0 < K; k0 += 64) {
    stage_tile(Ap + k0 * 2, ldab, smA, t);
    stage_tile(Bp + k0 * 2, ldbb, smB, t);
    __syncthreads();
    bf16x8 af[4][2], bf[4][2];
#pragma unroll
    for (int f = 0; f < 4; ++f)
#pragma unroll
      for (int ksl = 0; ksl < 2; ++ksl) {
        af[f][ksl] = read_frag(smA, wm * 64 + f * 16 + rl, ksl * 64 + kq * 16);
        bf[f][ksl] = read_frag(smB, wn * 64 + f * 16 + rl, ksl * 64 + kq * 16);
      }
#pragma unroll
    for (int fm = 0; fm < 4; ++fm)
#pragma unroll
      for (int fn = 0; fn < 4; ++fn) {
        acc[fm][fn] = MFMA16(af[fm][0], bf[fn][0], acc[fm][fn]);
        acc[fm][fn] = MFMA16(af[fm][1], bf[fn][1], acc[fm][fn]);
      }
    __syncthreads();
  }

  // Epilogue. C/D layout: col = lane&15, row = (lane>>4)*4 + reg  [m89-verified]
#pragma unroll
  for (int fm = 0; fm < 4; ++fm)
#pragma unroll
    for (int fn = 0; fn < 4; ++fn)
#pragma unroll
      for (int j = 0; j < 4; ++j) {
        int row = by * 128 + wm * 64 + fm * 16 + kq * 4 + j;
        int col = bx * 128 + wn * 64 + fn * 16 + rl;
        if (MODE == 0) {
          ((u16*)Cv)[(long long)b * sC + (long long)row * ldc + col] = f2bf(acc[fm][fn][j]);
        } else {
          ((float*)Cv)[((long long)(ks * 8 + b)) * sC + (long long)row * ldc + col] =
              acc[fm][fn][j];
        }
      }
}

// ---------------------------------------------------------------------------
// PV split-K combine: out = xq + sum of 4 partials. Fixed order, vectorized.
// 524288 float4's -> 2048 blocks x 256.
// ---------------------------------------------------------------------------
__global__ void pv_combine(const float* __restrict__ part, const float* __restrict__ xq,
                           float* __restrict__ out) {
  int i = blockIdx.x * 256 + threadIdx.x;
  float4 s = ((const float4*)xq)[i];
#pragma unroll
  for (int k = 0; k < 4; ++k) {
    float4 p = ((const float4*)(part + (long long)k * 2097152))[i];
    s.x += p.x; s.y += p.y; s.z += p.z; s.w += p.w;
  }
  ((float4*)out)[i] = s;
}

// ---------------------------------------------------------------------------
// Pass 1: tile-structured row sums of exp(S), no max shift (scores ~N(0,1)
// by construction; f32 sumexp has ~30 orders of headroom).
// K is the MFMA A-operand -> C rows = keys, C cols = q. Row-sum over keys is
// a per-thread register reduction + 2 shfl_xor over kq lane-groups.
// Per-wm partials -> 64 slices, combined by stats_combine (deterministic).
// grid = (kt=32, qt=2, z=16: m=z>>1, hhalf=z&1), block = 256 (2x2 waves).
// ---------------------------------------------------------------------------
__global__ __launch_bounds__(256, 4) void attn_stats(
    const u16* __restrict__ qg, const u16* __restrict__ kg,
    float* __restrict__ lstP) {
  __shared__ __align__(16) char smQ[16384];
  __shared__ __align__(16) char smK[16384];
  int kt = blockIdx.x, qt = blockIdx.y;
  int m = blockIdx.z >> 1, hh = blockIdx.z & 1;
  int t = threadIdx.x, lane = t & 63;
  int wm = t >> 7, wn = (t >> 6) & 1;
  int rl = lane & 15, kq = lane >> 4;

  const char* qbase = (const char*)(qg + ((long long)(m * NQ_ + qt * 128)) * 1024);
  const char* kbase = (const char*)(kg + ((long long)(m * NKV_ + kt * 128)) * 1024);

  for (int hi = 0; hi < 8; ++hi) {
    int h = hh * 8 + hi;
    stage_tile(qbase + h * 128, 2048, smQ, t);
    stage_tile(kbase + h * 128, 2048, smK, t);
    __syncthreads();
    bf16x8 kf[4][2], qf[4][2];
#pragma unroll
    for (int f = 0; f < 4; ++f)
#pragma unroll
      for (int ksl = 0; ksl < 2; ++ksl) {
        kf[f][ksl] = read_frag(smK, wm * 64 + f * 16 + rl, ksl * 64 + kq * 16);
        qf[f][ksl] = read_frag(smQ, wn * 64 + f * 16 + rl, ksl * 64 + kq * 16);
      }
    float rs[4] = {0.f, 0.f, 0.f, 0.f};
#pragma unroll
    for (int fm = 0; fm < 4; ++fm)
#pragma unroll
      for (int fn = 0; fn < 4; ++fn) {
        f32x4 sc = (f32x4){0.f, 0.f, 0.f, 0.f};
        sc = MFMA16(kf[fm][0], qf[fn][0], sc);
        sc = MFMA16(kf[fm][1], qf[fn][1], sc);
        rs[fn] += (__expf(sc[0]) + __expf(sc[1])) + (__expf(sc[2]) + __expf(sc[3]));
      }
#pragma unroll
    for (int fn = 0; fn < 4; ++fn) {
      float v = rs[fn];
      v += __shfl_xor(v, 16);
      v += __shfl_xor(v, 32);
      if (lane < 16) {
        int q = qt * 128 + wn * 64 + fn * 16 + rl;
        lstP[(long long)(kt * 2 + wm) * 32768 + ((m * H_ + h) << 8) + q] = v;
      }
    }
    __syncthreads();
  }
}

// ---------------------------------------------------------------------------
// Merge the 64 (kt x wm) partial sums. Fixed order -> deterministic.
// ---------------------------------------------------------------------------
__global__ void stats_combine(const float* __restrict__ lp, float* __restrict__ lst) {
  int i = blockIdx.x * 256 + threadIdx.x;
  float s = 0.f;
#pragma unroll
  for (int k = 0; k < 64; ++k) s += lp[(long long)k * 32768 + i];
  lst[i] = s;
}

// ---------------------------------------------------------------------------
// Pass 2: Pbar[m,q,k] = sum_h (hw[h]/l[m,h,q]) * exp(s_h), bf16 out (no max).
// grid = (kt=32, qt=2, m=8), block = 256.
// ---------------------------------------------------------------------------
__global__ __launch_bounds__(256, 2) void pbar_kernel(
    const u16* __restrict__ qg, const u16* __restrict__ kg,
    const float* __restrict__ lstat,
    const float* __restrict__ rawhw, u16* __restrict__ Pbar) {
  __shared__ __align__(16) char smQ[16384];
  __shared__ __align__(16) char smK[16384];
  __shared__ float scf[2048];
  int kt = blockIdx.x, qt = blockIdx.y, m = blockIdx.z;
  int q0 = qt * 128, k0 = kt * 128;
  int t = threadIdx.x, lane = t & 63;
  int wm = t >> 7, wn = (t >> 6) & 1;
  int rl = lane & 15, kq = lane >> 4;

  // head-weight softmax (redundant per thread; 16 elements, L1-served)
  float hm = -1e30f;
  for (int i = 0; i < H_; ++i) hm = fmaxf(hm, rawhw[i]);
  float hs = 0.f, hw[H_];
  for (int i = 0; i < H_; ++i) { hw[i] = __expf(rawhw[i] - hm); hs += hw[i]; }
  float hinv = 1.f / hs;
  for (int idx = t; idx < 2048; idx += 256) {
    int h = idx >> 7, r = idx & 127;
    scf[idx] = hw[h] * hinv / lstat[((m * H_ + h) << 8) + q0 + r];
  }

  f32x4 pacc[4][4];
#pragma unroll
  for (int i = 0; i < 4; ++i)
#pragma unroll
    for (int j = 0; j < 4; ++j) pacc[i][j] = (f32x4){0.f, 0.f, 0.f, 0.f};

  const char* qbase = (const char*)(qg + ((long long)(m * NQ_ + q0)) * 1024);
  const char* kbase = (const char*)(kg + ((long long)(m * NKV_ + k0)) * 1024);

  for (int h = 0; h < H_; ++h) {
    stage_tile(qbase + h * 128, 2048, smQ, t);
    stage_tile(kbase + h * 128, 2048, smK, t);
    __syncthreads();  // also orders the scf writes above (first iter)
    bf16x8 af[4][2], bfr[4][2];
#pragma unroll
    for (int f = 0; f < 4; ++f)
#pragma unroll
      for (int ksl = 0; ksl < 2; ++ksl) {
        af[f][ksl] = read_frag(smQ, wm * 64 + f * 16 + rl, ksl * 64 + kq * 16);
        bfr[f][ksl] = read_frag(smK, wn * 64 + f * 16 + rl, ksl * 64 + kq * 16);
      }
#pragma unroll
    for (int fm = 0; fm < 4; ++fm) {
      int rbase = wm * 64 + fm * 16 + kq * 4;
      float cf0 = scf[(h << 7) + rbase + 0];
      float cf1 = scf[(h << 7) + rbase + 1];
      float cf2 = scf[(h << 7) + rbase + 2];
      float cf3 = scf[(h << 7) + rbase + 3];
#pragma unroll
      for (int fn = 0; fn < 4; ++fn) {
        f32x4 sc = (f32x4){0.f, 0.f, 0.f, 0.f};
        sc = MFMA16(af[fm][0], bfr[fn][0], sc);
        sc = MFMA16(af[fm][1], bfr[fn][1], sc);
        pacc[fm][fn][0] += cf0 * __expf(sc[0]);
        pacc[fm][fn][1] += cf1 * __expf(sc[1]);
        pacc[fm][fn][2] += cf2 * __expf(sc[2]);
        pacc[fm][fn][3] += cf3 * __expf(sc[3]);
      }
    }
    __syncthreads();
  }
#pragma unroll
  for (int fm = 0; fm < 4; ++fm)
#pragma unroll
    for (int fn = 0; fn < 4; ++fn)
#pragma unroll
      for (int j = 0; j < 4; ++j) {
        int row = q0 + wm * 64 + fm * 16 + kq * 4 + j;
        int col = k0 + wn * 64 + fn * 16 + rl;
        Pbar[(((long long)m * NQ_ + row) << 12) + col] = f2bf(pacc[fm][fn][j]);
      }
}

// ---------------------------------------------------------------------------
// f32 -> bf16 convert, 8 elements/thread
// ---------------------------------------------------------------------------
__global__ void cvt8(const float* __restrict__ in, u16* __restrict__ out, long long n8) {
  long long i = (long long)blockIdx.x * 256 + threadIdx.x;
  if (i >= n8) return;
  const float4* p = (const float4*)in + i * 2;
  float4 a = p[0], b = p[1];
  u16x8 v;
  v[0] = f2bf(a.x); v[1] = f2bf(a.y); v[2] = f2bf(a.z); v[3] = f2bf(a.w);
  v[4] = f2bf(b.x); v[5] = f2bf(b.y); v[6] = f2bf(b.z); v[7] = f2bf(b.w);
  *(u16x8*)(out + i * 8) = v;
}

// ---------------------------------------------------------------------------
// Transposed f32 -> bf16 convert (out[c][r] = alpha * in[r][c]), batched.
// block (32,8), 32x32 tiles.
// ---------------------------------------------------------------------------
__global__ void tcvt(const float* __restrict__ in, u16* __restrict__ out,
                     int R, int C, long long sIn, long long sOut, float alpha) {
  __shared__ float tile[32][33];
  long long bIn = (long long)blockIdx.z * sIn;
  long long bOut = (long long)blockIdx.z * sOut;
  int c0 = blockIdx.x * 32, r0 = blockIdx.y * 32;
  int tx = threadIdx.x, ty = threadIdx.y;
#pragma unroll
  for (int i = 0; i < 32; i += 8)
    tile[ty + i][tx] = in[bIn + (long long)(r0 + ty + i) * C + c0 + tx];
  __syncthreads();
#pragma unroll
  for (int i = 0; i < 32; i += 8)
    out[bOut + (long long)(c0 + ty + i) * R + r0 + tx] = f2bf(alpha * tile[tx][ty + i]);
}

// ---------------------------------------------------------------------------
extern "C" void kernel_launch(void* const* d_in, const int* in_sizes, int n_in,
                              void* d_out, int out_size, void* d_ws, size_t ws_size,
                              hipStream_t stream) {
  const float* zq  = (const float*)d_in[0];
  const float* zkv = (const float*)d_in[1];
  const float* xq  = (const float*)d_in[2];
  const float* xkv = (const float*)d_in[3];
  const float* Wq  = (const float*)d_in[4];
  const float* Wk  = (const float*)d_in[5];
  const float* rhw = (const float*)d_in[6];
  float* out = (float*)d_out;

  // Workspace layout (bytes). Total need: ~204 MB.
  char* ws = (char*)d_ws;
  u16* WqT  = (u16*)(ws);                      //  2 MB  [1024][1024] (x0.125 folded)
  u16* WkT  = (u16*)(ws + (2ull << 20));       //  2 MB
  u16* zqb  = (u16*)(ws + (4ull << 20));       //  4 MB  [2048][1024]
  u16* qb   = (u16*)(ws + (8ull << 20));       //  4 MB  [2048][1024] (pre-scaled)
  u16* kb   = (u16*)(ws + (12ull << 20));      // 64 MB  [32768][1024]
  u16* xkvT = (u16*)(ws + (76ull << 20));      // 64 MB  [8][1024][4096]
  char* zr  = ws + (140ull << 20);             // 64 MB region, dual-use:
  u16* zkvb = (u16*)zr;                        //   zkv bf16 (dead after Kproj)
  u16* Pbar = (u16*)zr;                        //   then Pbar [8][256][4096] (16 MB)
  float* lst  = (float*)(zr + (18ull << 20));  //   final sumexp (128 KB)
  float* lstP = (float*)(zr + (20ull << 20));  //   partial sumexp [64][32768] (8 MB)
  float* pvP  = (float*)(zr + (28ull << 20));  //   PV split-K partials [4][8][256][1024] (32 MB)

  // 0. zq passthrough (output 0)
  hipMemcpyAsync(d_out, (const void*)zq, (size_t)MB_ * NQ_ * E_ * sizeof(float),
                 hipMemcpyDeviceToDevice, stream);

  // 1. converts (cvt8 restored per R5 post-mortem: in-GEMM f32 staging was 3x worse)
  cvt8<<<(MB_ * NQ_ * E_) / 8 / 256, 256, 0, stream>>>(zq, zqb, (MB_ * NQ_ * E_) / 8);
  cvt8<<<(MB_ * NKV_ * E_) / 8 / 256, 256, 0, stream>>>(zkv, zkvb, (long long)(MB_ * NKV_ * E_) / 8);
  dim3 tb(32, 8);
  tcvt<<<dim3(32, 32, 1), tb, 0, stream>>>(Wq, WqT, 1024, 1024, 0, 0, 0.125f);  // fold SCALE
  tcvt<<<dim3(32, 32, 1), tb, 0, stream>>>(Wk, WkT, 1024, 1024, 0, 0, 1.0f);
  tcvt<<<dim3(32, 128, 8), tb, 0, stream>>>(xkv, xkvT, NKV_, E_,
                                            (long long)NKV_ * E_, (long long)NKV_ * E_, 1.0f);

  // 2. projections (NT GEMM, bf16 in/out, global_load_lds staging)
  gemm_nt<0><<<dim3(8, 16, 1), 256, 0, stream>>>(zqb, WqT, qb,
                                                 1024, 1024, 1024, 1024, 0, 0, 0);
  gemm_nt<0><<<dim3(8, 256, 1), 256, 0, stream>>>(zkvb, WkT, kb,
                                                  1024, 1024, 1024, 1024, 0, 0, 0);

  // 3. softmax denominators: tile-structured partial sums, then combine
  attn_stats<<<dim3(32, 2, 16), 256, 0, stream>>>(qb, kb, lstP);
  stats_combine<<<128, 256, 0, stream>>>(lstP, lst);

  // 4. head-collapsed probabilities
  pbar_kernel<<<dim3(32, 2, 8), 256, 0, stream>>>(qb, kb, lst, rhw, Pbar);

  // 5. PV split-K x4 -> f32 partials, then combine with residual
  gemm_nt<2><<<dim3(8, 2, 32), 256, 0, stream>>>(Pbar, xkvT, pvP,
                                                 4096, 4096, 1024, 1024,
                                                 256LL * 4096, 1024LL * 4096,
                                                 256LL * 1024);
  pv_combine<<<2048, 256, 0, stream>>>(pvP, xq, out + (long long)MB_ * NQ_ * E_);
}

// Round 7
// 312.505 us; speedup vs baseline: 1.5910x; 1.0048x over previous
//
#include <hip/hip_runtime.h>
#include <hip/hip_bf16.h>
#include <stdint.h>

// Problem constants
#define MB_  8
#define NQ_  256
#define NKV_ 4096
#define E_   1024
#define H_   16
#define D_   64

typedef __bf16 bf16x8 __attribute__((ext_vector_type(8)));
typedef float  f32x4  __attribute__((ext_vector_type(4)));
typedef unsigned short u16;
typedef unsigned short u16x8 __attribute__((ext_vector_type(8)));

#define MFMA16(a,b,c) __builtin_amdgcn_mfma_f32_16x16x32_bf16((a),(b),(c),0,0,0)

__device__ __forceinline__ u16 f2bf(float f) {
  uint32_t u = __float_as_uint(f);
  u += 0x7fffu + ((u >> 16) & 1u);   // RNE (no NaNs in this workload)
  return (u16)(u >> 16);
}

__device__ __forceinline__ void gload_lds16(const void* g, void* l) {
  __builtin_amdgcn_global_load_lds(
      (const __attribute__((address_space(1))) void*)g,
      (__attribute__((address_space(3))) void*)l, 16, 0, 0);
}

// Stage a 128-row x 128-byte bf16 tile (row stride ldbytes) into LDS.
// Swizzle applied via the GLOBAL source address (rule #21): LDS byte (row,cb)
// holds source (row, cb ^ ((row&7)<<4)).
// NOTE (R5 post-mortem): reg-staged f32->bf16 fusion here regressed 3x
// (serialized load->wait->ds_write->barrier, no async overlap). Keep
// global_load_lds staging; do dtype converts in separate HBM-bound kernels.
__device__ __forceinline__ void stage_tile(const char* __restrict__ g, int ldbytes,
                                           char* lds, int t) {
  int srcCB = (((t & 7) ^ ((t >> 3) & 7)) << 4);
  const char* gp = g + (long long)(t >> 3) * ldbytes + srcCB;
  char* lp = lds + ((t >> 6) << 10);
#pragma unroll
  for (int i = 0; i < 4; ++i) {
    gload_lds16(gp + (long long)(32 * i) * ldbytes, lp + i * 4096);
  }
}

// Read one MFMA fragment (8 contiguous bf16 at (row r, col-byte cb)) with swizzle.
__device__ __forceinline__ bf16x8 read_frag(const char* lds, int r, int cb) {
  return *(const bf16x8*)(lds + r * 128 + (cb ^ ((r & 7) << 4)));
}

// ---------------------------------------------------------------------------
// Generic NT GEMM: C[M x N] = A[M x K] @ Bt[N x K]^T, bf16 in, f32 acc.
// MODE 0: store bf16 C.
// MODE 2: split-K x4 -> f32 partials; z encodes (ks = z>>3, m = z&7), each
//         split covers K=1024. Combined by pv_combine_copy (fixed order).
// 128x128 tile, BK=64, 256 threads (2x2 waves, each 64x64).
// XCD-aware bijective swizzle (m157): (gridDim.x*gridDim.y) % 8 == 0 holds
// for all launches here. At MfmaUtil ~34% this is AT the m97-structure
// ceiling (m98: 37%); next step would be the 8-phase 256^2 schedule.
// ---------------------------------------------------------------------------
template <int MODE>
__global__ __launch_bounds__(256, 2) void gemm_nt(
    const u16* __restrict__ A, const u16* __restrict__ Bt, void* __restrict__ Cv,
    int lda, int ldb, int ldc, int K,
    long long sA, long long sB, long long sC) {
  __shared__ __align__(16) char smA[16384];
  __shared__ __align__(16) char smB[16384];
  int zz = blockIdx.z;
  int b = (MODE == 2) ? (zz & 7) : zz;
  int ks = (MODE == 2) ? (zz >> 3) : 0;
  long long koff = (long long)ks * 1024;

  // XCD swizzle: keep same-A-panel blocks on one XCD
  unsigned nwg = gridDim.x * gridDim.y;
  unsigned orig = blockIdx.y * gridDim.x + blockIdx.x;
  unsigned cpx = nwg >> 3;
  unsigned swz = (orig & 7) * cpx + (orig >> 3);
  unsigned bx = swz % gridDim.x, by = swz / gridDim.x;

  const char* Ap = (const char*)(A + (long long)b * sA + (long long)by * 128 * lda + koff);
  const char* Bp = (const char*)(Bt + (long long)b * sB + (long long)bx * 128 * ldb + koff);

  int t = threadIdx.x, lane = t & 63;
  int wm = t >> 7, wn = (t >> 6) & 1;
  int rl = lane & 15, kq = lane >> 4;

  f32x4 acc[4][4];
#pragma unroll
  for (int i = 0; i < 4; ++i)
#pragma unroll
    for (int j = 0; j < 4; ++j) acc[i][j] = (f32x4){0.f, 0.f, 0.f, 0.f};

  int ldab = lda * 2, ldbb = ldb * 2;
  for (int k0 = 0; k0 < K; k0 += 64) {
    stage_tile(Ap + k0 * 2, ldab, smA, t);
    stage_tile(Bp + k0 * 2, ldbb, smB, t);
    __syncthreads();
    bf16x8 af[4][2], bf[4][2];
#pragma unroll
    for (int f = 0; f < 4; ++f)
#pragma unroll
      for (int ksl = 0; ksl < 2; ++ksl) {
        af[f][ksl] = read_frag(smA, wm * 64 + f * 16 + rl, ksl * 64 + kq * 16);
        bf[f][ksl] = read_frag(smB, wn * 64 + f * 16 + rl, ksl * 64 + kq * 16);
      }
#pragma unroll
    for (int fm = 0; fm < 4; ++fm)
#pragma unroll
      for (int fn = 0; fn < 4; ++fn) {
        acc[fm][fn] = MFMA16(af[fm][0], bf[fn][0], acc[fm][fn]);
        acc[fm][fn] = MFMA16(af[fm][1], bf[fn][1], acc[fm][fn]);
      }
    __syncthreads();
  }

  // Epilogue. C/D layout: col = lane&15, row = (lane>>4)*4 + reg  [m89-verified]
#pragma unroll
  for (int fm = 0; fm < 4; ++fm)
#pragma unroll
    for (int fn = 0; fn < 4; ++fn)
#pragma unroll
      for (int j = 0; j < 4; ++j) {
        int row = by * 128 + wm * 64 + fm * 16 + kq * 4 + j;
        int col = bx * 128 + wn * 64 + fn * 16 + rl;
        if (MODE == 0) {
          ((u16*)Cv)[(long long)b * sC + (long long)row * ldc + col] = f2bf(acc[fm][fn][j]);
        } else {
          ((float*)Cv)[((long long)(ks * 8 + b)) * sC + (long long)row * ldc + col] =
              acc[fm][fn][j];
        }
      }
}

// ---------------------------------------------------------------------------
// Merged: zq passthrough copy (output 0) + PV split-K combine (output 1).
// blocks [0,2048): out0 = zq (float4 copy).
// blocks [2048,4096): out1 = xq + sum of 4 PV partials. Fixed order.
// ---------------------------------------------------------------------------
__global__ void pv_combine_copy(const float* __restrict__ part, const float* __restrict__ xq,
                                const float* __restrict__ zq, float* __restrict__ out0,
                                float* __restrict__ out1) {
  int bid = blockIdx.x;
  if (bid < 2048) {
    int i = bid * 256 + threadIdx.x;
    ((float4*)out0)[i] = ((const float4*)zq)[i];
  } else {
    int i = (bid - 2048) * 256 + threadIdx.x;
    float4 s = ((const float4*)xq)[i];
#pragma unroll
    for (int k = 0; k < 4; ++k) {
      float4 p = ((const float4*)(part + (long long)k * 2097152))[i];
      s.x += p.x; s.y += p.y; s.z += p.z; s.w += p.w;
    }
    ((float4*)out1)[i] = s;
  }
}

// ---------------------------------------------------------------------------
// Pass 1: tile-structured row sums of exp(S), no max shift (scores ~N(0,1)
// by construction; f32 sumexp has ~30 orders of headroom).
// K is the MFMA A-operand -> C rows = keys, C cols = q. Row-sum over keys is
// a per-thread register reduction + 2 shfl_xor over kq lane-groups.
// Per-wm partials -> 64 slices, combined by stats_combine (deterministic).
// grid = (kt=32, qt=2, z=16: m=z>>1, hhalf=z&1), block = 256 (2x2 waves).
// ---------------------------------------------------------------------------
__global__ __launch_bounds__(256, 4) void attn_stats(
    const u16* __restrict__ qg, const u16* __restrict__ kg,
    float* __restrict__ lstP) {
  __shared__ __align__(16) char smQ[16384];
  __shared__ __align__(16) char smK[16384];
  int kt = blockIdx.x, qt = blockIdx.y;
  int m = blockIdx.z >> 1, hh = blockIdx.z & 1;
  int t = threadIdx.x, lane = t & 63;
  int wm = t >> 7, wn = (t >> 6) & 1;
  int rl = lane & 15, kq = lane >> 4;

  const char* qbase = (const char*)(qg + ((long long)(m * NQ_ + qt * 128)) * 1024);
  const char* kbase = (const char*)(kg + ((long long)(m * NKV_ + kt * 128)) * 1024);

  for (int hi = 0; hi < 8; ++hi) {
    int h = hh * 8 + hi;
    stage_tile(qbase + h * 128, 2048, smQ, t);
    stage_tile(kbase + h * 128, 2048, smK, t);
    __syncthreads();
    bf16x8 kf[4][2], qf[4][2];
#pragma unroll
    for (int f = 0; f < 4; ++f)
#pragma unroll
      for (int ksl = 0; ksl < 2; ++ksl) {
        kf[f][ksl] = read_frag(smK, wm * 64 + f * 16 + rl, ksl * 64 + kq * 16);
        qf[f][ksl] = read_frag(smQ, wn * 64 + f * 16 + rl, ksl * 64 + kq * 16);
      }
    float rs[4] = {0.f, 0.f, 0.f, 0.f};
#pragma unroll
    for (int fm = 0; fm < 4; ++fm)
#pragma unroll
      for (int fn = 0; fn < 4; ++fn) {
        f32x4 sc = (f32x4){0.f, 0.f, 0.f, 0.f};
        sc = MFMA16(kf[fm][0], qf[fn][0], sc);
        sc = MFMA16(kf[fm][1], qf[fn][1], sc);
        rs[fn] += (__expf(sc[0]) + __expf(sc[1])) + (__expf(sc[2]) + __expf(sc[3]));
      }
#pragma unroll
    for (int fn = 0; fn < 4; ++fn) {
      float v = rs[fn];
      v += __shfl_xor(v, 16);
      v += __shfl_xor(v, 32);
      if (lane < 16) {
        int q = qt * 128 + wn * 64 + fn * 16 + rl;
        lstP[(long long)(kt * 2 + wm) * 32768 + ((m * H_ + h) << 8) + q] = v;
      }
    }
    __syncthreads();
  }
}

// ---------------------------------------------------------------------------
// Merge the 64 (kt x wm) partial sums. Fixed order -> deterministic.
// ---------------------------------------------------------------------------
__global__ void stats_combine(const float* __restrict__ lp, float* __restrict__ lst) {
  int i = blockIdx.x * 256 + threadIdx.x;
  float s = 0.f;
#pragma unroll
  for (int k = 0; k < 64; ++k) s += lp[(long long)k * 32768 + i];
  lst[i] = s;
}

// ---------------------------------------------------------------------------
// Pass 2: Pbar[m,q,k] = sum_h (hw[h]/l[m,h,q]) * exp(s_h), bf16 out (no max).
// grid = (kt=32, qt=2, m=8), block = 256.
// ---------------------------------------------------------------------------
__global__ __launch_bounds__(256, 2) void pbar_kernel(
    const u16* __restrict__ qg, const u16* __restrict__ kg,
    const float* __restrict__ lstat,
    const float* __restrict__ rawhw, u16* __restrict__ Pbar) {
  __shared__ __align__(16) char smQ[16384];
  __shared__ __align__(16) char smK[16384];
  __shared__ float scf[2048];
  int kt = blockIdx.x, qt = blockIdx.y, m = blockIdx.z;
  int q0 = qt * 128, k0 = kt * 128;
  int t = threadIdx.x, lane = t & 63;
  int wm = t >> 7, wn = (t >> 6) & 1;
  int rl = lane & 15, kq = lane >> 4;

  // head-weight softmax (redundant per thread; 16 elements, L1-served)
  float hm = -1e30f;
  for (int i = 0; i < H_; ++i) hm = fmaxf(hm, rawhw[i]);
  float hs = 0.f, hw[H_];
  for (int i = 0; i < H_; ++i) { hw[i] = __expf(rawhw[i] - hm); hs += hw[i]; }
  float hinv = 1.f / hs;
  for (int idx = t; idx < 2048; idx += 256) {
    int h = idx >> 7, r = idx & 127;
    scf[idx] = hw[h] * hinv / lstat[((m * H_ + h) << 8) + q0 + r];
  }

  f32x4 pacc[4][4];
#pragma unroll
  for (int i = 0; i < 4; ++i)
#pragma unroll
    for (int j = 0; j < 4; ++j) pacc[i][j] = (f32x4){0.f, 0.f, 0.f, 0.f};

  const char* qbase = (const char*)(qg + ((long long)(m * NQ_ + q0)) * 1024);
  const char* kbase = (const char*)(kg + ((long long)(m * NKV_ + k0)) * 1024);

  for (int h = 0; h < H_; ++h) {
    stage_tile(qbase + h * 128, 2048, smQ, t);
    stage_tile(kbase + h * 128, 2048, smK, t);
    __syncthreads();  // also orders the scf writes above (first iter)
    bf16x8 af[4][2], bfr[4][2];
#pragma unroll
    for (int f = 0; f < 4; ++f)
#pragma unroll
      for (int ksl = 0; ksl < 2; ++ksl) {
        af[f][ksl] = read_frag(smQ, wm * 64 + f * 16 + rl, ksl * 64 + kq * 16);
        bfr[f][ksl] = read_frag(smK, wn * 64 + f * 16 + rl, ksl * 64 + kq * 16);
      }
#pragma unroll
    for (int fm = 0; fm < 4; ++fm) {
      int rbase = wm * 64 + fm * 16 + kq * 4;
      float cf0 = scf[(h << 7) + rbase + 0];
      float cf1 = scf[(h << 7) + rbase + 1];
      float cf2 = scf[(h << 7) + rbase + 2];
      float cf3 = scf[(h << 7) + rbase + 3];
#pragma unroll
      for (int fn = 0; fn < 4; ++fn) {
        f32x4 sc = (f32x4){0.f, 0.f, 0.f, 0.f};
        sc = MFMA16(af[fm][0], bfr[fn][0], sc);
        sc = MFMA16(af[fm][1], bfr[fn][1], sc);
        pacc[fm][fn][0] += cf0 * __expf(sc[0]);
        pacc[fm][fn][1] += cf1 * __expf(sc[1]);
        pacc[fm][fn][2] += cf2 * __expf(sc[2]);
        pacc[fm][fn][3] += cf3 * __expf(sc[3]);
      }
    }
    __syncthreads();
  }
#pragma unroll
  for (int fm = 0; fm < 4; ++fm)
#pragma unroll
    for (int fn = 0; fn < 4; ++fn)
#pragma unroll
      for (int j = 0; j < 4; ++j) {
        int row = q0 + wm * 64 + fm * 16 + kq * 4 + j;
        int col = k0 + wn * 64 + fn * 16 + rl;
        Pbar[(((long long)m * NQ_ + row) << 12) + col] = f2bf(pacc[fm][fn][j]);
      }
}

// ---------------------------------------------------------------------------
// Merged f32 -> bf16 convert for zq (blocks [0,1024)) and zkv (rest).
// 8 elements/thread, float4 reads, u16x8 writes.
// ---------------------------------------------------------------------------
__global__ void cvt8m(const float* __restrict__ zq, u16* __restrict__ zqb,
                      const float* __restrict__ zkv, u16* __restrict__ zkvb) {
  int bid = blockIdx.x;
  const float* in;
  u16* out;
  long long i;
  if (bid < 1024) { in = zq; out = zqb; i = (long long)bid * 256 + threadIdx.x; }
  else { in = zkv; out = zkvb; i = (long long)(bid - 1024) * 256 + threadIdx.x; }
  const float4* p = (const float4*)in + i * 2;
  float4 a = p[0], b = p[1];
  u16x8 v;
  v[0] = f2bf(a.x); v[1] = f2bf(a.y); v[2] = f2bf(a.z); v[3] = f2bf(a.w);
  v[4] = f2bf(b.x); v[5] = f2bf(b.y); v[6] = f2bf(b.z); v[7] = f2bf(b.w);
  *(u16x8*)(out + i * 8) = v;
}

// ---------------------------------------------------------------------------
// Transposed f32 -> bf16 convert (out[c][r] = alpha * in[r][c]), batched.
// 64x64 tiles, block 256. float4 global reads; 16B (uint4 = 8 u16) global
// writes. LDS [64][65]: both phases verified <= 2-way bank aliasing (free).
// grid = (R/64, C/64, batches).
// ---------------------------------------------------------------------------
__global__ void tcvt64(const float* __restrict__ in, u16* __restrict__ out,
                       int R, int C, long long sIn, long long sOut, float alpha) {
  __shared__ float tile[64][65];
  in += (long long)blockIdx.z * sIn;
  out += (long long)blockIdx.z * sOut;
  int r0 = blockIdx.x * 64, c0 = blockIdx.y * 64;
  int t = threadIdx.x;
  int rr = t >> 4, c4 = t & 15;
#pragma unroll
  for (int i = 0; i < 4; ++i) {
    float4 v = *(const float4*)(in + (long long)(r0 + rr + i * 16) * C + c0 + c4 * 4);
    float* d = &tile[rr + i * 16][c4 * 4];
    d[0] = v.x; d[1] = v.y; d[2] = v.z; d[3] = v.w;
  }
  __syncthreads();
  int cc = t >> 3, r8 = t & 7;
#pragma unroll
  for (int i = 0; i < 2; ++i) {
    int c = cc + i * 32;
    u16x8 v;
#pragma unroll
    for (int j = 0; j < 8; ++j) v[j] = f2bf(alpha * tile[r8 * 8 + j][c]);
    *(u16x8*)(out + (long long)(c0 + c) * R + r0 + r8 * 8) = v;
  }
}

// ---------------------------------------------------------------------------
extern "C" void kernel_launch(void* const* d_in, const int* in_sizes, int n_in,
                              void* d_out, int out_size, void* d_ws, size_t ws_size,
                              hipStream_t stream) {
  const float* zq  = (const float*)d_in[0];
  const float* zkv = (const float*)d_in[1];
  const float* xq  = (const float*)d_in[2];
  const float* xkv = (const float*)d_in[3];
  const float* Wq  = (const float*)d_in[4];
  const float* Wk  = (const float*)d_in[5];
  const float* rhw = (const float*)d_in[6];
  float* out = (float*)d_out;

  // Workspace layout (bytes). Total need: ~204 MB.
  char* ws = (char*)d_ws;
  u16* WqT  = (u16*)(ws);                      //  2 MB  [1024][1024] (x0.125 folded)
  u16* WkT  = (u16*)(ws + (2ull << 20));       //  2 MB
  u16* zqb  = (u16*)(ws + (4ull << 20));       //  4 MB  [2048][1024]
  u16* qb   = (u16*)(ws + (8ull << 20));       //  4 MB  [2048][1024] (pre-scaled)
  u16* kb   = (u16*)(ws + (12ull << 20));      // 64 MB  [32768][1024]
  u16* xkvT = (u16*)(ws + (76ull << 20));      // 64 MB  [8][1024][4096]
  char* zr  = ws + (140ull << 20);             // 64 MB region, dual-use:
  u16* zkvb = (u16*)zr;                        //   zkv bf16 (dead after Kproj)
  u16* Pbar = (u16*)zr;                        //   then Pbar [8][256][4096] (16 MB)
  float* lst  = (float*)(zr + (18ull << 20));  //   final sumexp (128 KB)
  float* lstP = (float*)(zr + (20ull << 20));  //   partial sumexp [64][32768] (8 MB)
  float* pvP  = (float*)(zr + (28ull << 20));  //   PV split-K partials [4][8][256][1024] (32 MB)

  // 1. converts (merged launches; tcvt64 = vectorized 16B-write transpose)
  cvt8m<<<17408, 256, 0, stream>>>(zq, zqb, zkv, zkvb);
  tcvt64<<<dim3(16, 16, 1), 256, 0, stream>>>(Wq, WqT, 1024, 1024, 0, 0, 0.125f);  // fold SCALE
  tcvt64<<<dim3(16, 16, 1), 256, 0, stream>>>(Wk, WkT, 1024, 1024, 0, 0, 1.0f);
  tcvt64<<<dim3(64, 16, 8), 256, 0, stream>>>(xkv, xkvT, NKV_, E_,
                                              (long long)NKV_ * E_, (long long)NKV_ * E_, 1.0f);

  // 2. projections (NT GEMM, bf16 in/out, global_load_lds staging)
  gemm_nt<0><<<dim3(8, 16, 1), 256, 0, stream>>>(zqb, WqT, qb,
                                                 1024, 1024, 1024, 1024, 0, 0, 0);
  gemm_nt<0><<<dim3(8, 256, 1), 256, 0, stream>>>(zkvb, WkT, kb,
                                                  1024, 1024, 1024, 1024, 0, 0, 0);

  // 3. softmax denominators: tile-structured partial sums, then combine
  attn_stats<<<dim3(32, 2, 16), 256, 0, stream>>>(qb, kb, lstP);
  stats_combine<<<128, 256, 0, stream>>>(lstP, lst);

  // 4. head-collapsed probabilities
  pbar_kernel<<<dim3(32, 2, 8), 256, 0, stream>>>(qb, kb, lst, rhw, Pbar);

  // 5. PV split-K x4 -> f32 partials, then combine with residual + zq copy
  gemm_nt<2><<<dim3(8, 2, 32), 256, 0, stream>>>(Pbar, xkvT, pvP,
                                                 4096, 4096, 1024, 1024,
                                                 256LL * 4096, 1024LL * 4096,
                                                 256LL * 1024);
  pv_combine_copy<<<4096, 256, 0, stream>>>(pvP, xq, zq, out,
                                            out + (long long)MB_ * NQ_ * E_);
}

// Round 8
// 300.863 us; speedup vs baseline: 1.6526x; 1.0387x over previous
//
#include <hip/hip_runtime.h>
#include <hip/hip_bf16.h>
#include <stdint.h>

// Problem constants
#define MB_  8
#define NQ_  256
#define NKV_ 4096
#define E_   1024
#define H_   16
#define D_   64

typedef __bf16 bf16x8 __attribute__((ext_vector_type(8)));
typedef float  f32x4  __attribute__((ext_vector_type(4)));
typedef unsigned short u16;
typedef unsigned short u16x8 __attribute__((ext_vector_type(8)));

#define MFMA16(a,b,c) __builtin_amdgcn_mfma_f32_16x16x32_bf16((a),(b),(c),0,0,0)

__device__ __forceinline__ u16 f2bf(float f) {
  uint32_t u = __float_as_uint(f);
  u += 0x7fffu + ((u >> 16) & 1u);   // RNE (no NaNs in this workload)
  return (u16)(u >> 16);
}

__device__ __forceinline__ void gload_lds16(const void* g, void* l) {
  __builtin_amdgcn_global_load_lds(
      (const __attribute__((address_space(1))) void*)g,
      (__attribute__((address_space(3))) void*)l, 16, 0, 0);
}

// Stage a 128-row x 128-byte bf16 tile (row stride ldbytes) into LDS.
// Swizzle via the GLOBAL source address (rule #21): LDS byte (row,cb) holds
// source (row, cb ^ ((row&7)<<4)). LDS dest pointer is wave-uniform;
// HW adds lane*16 (m104/m108).
__device__ __forceinline__ void stage_tile(const char* __restrict__ g, int ldbytes,
                                           char* lds, int t) {
  int srcCB = (((t & 7) ^ ((t >> 3) & 7)) << 4);
  const char* gp = g + (long long)(t >> 3) * ldbytes + srcCB;
  char* lp = lds + ((t >> 6) << 10);
#pragma unroll
  for (int i = 0; i < 4; ++i) {
    gload_lds16(gp + (long long)(32 * i) * ldbytes, lp + i * 4096);
  }
}

// Read one MFMA fragment (8 contiguous bf16 at (row r, col-byte cb)) with swizzle.
__device__ __forceinline__ bf16x8 read_frag(const char* lds, int r, int cb) {
  return *(const bf16x8*)(lds + r * 128 + (cb ^ ((r & 7) << 4)));
}

// ---------------------------------------------------------------------------
// Generic NT GEMM (128x128 tile, BK=64, 256 thr). MODE 0: bf16 C.
// MODE 2: split-K x4 f32 partials (z = ks*8 + m). Used for Qproj + PV.
// ---------------------------------------------------------------------------
template <int MODE>
__global__ __launch_bounds__(256, 2) void gemm_nt(
    const u16* __restrict__ A, const u16* __restrict__ Bt, void* __restrict__ Cv,
    int lda, int ldb, int ldc, int K,
    long long sA, long long sB, long long sC) {
  __shared__ __align__(16) char smA[16384];
  __shared__ __align__(16) char smB[16384];
  int zz = blockIdx.z;
  int b = (MODE == 2) ? (zz & 7) : zz;
  int ks = (MODE == 2) ? (zz >> 3) : 0;
  long long koff = (long long)ks * 1024;

  unsigned nwg = gridDim.x * gridDim.y;
  unsigned orig = blockIdx.y * gridDim.x + blockIdx.x;
  unsigned cpx = nwg >> 3;
  unsigned swz = (orig & 7) * cpx + (orig >> 3);
  unsigned bx = swz % gridDim.x, by = swz / gridDim.x;

  const char* Ap = (const char*)(A + (long long)b * sA + (long long)by * 128 * lda + koff);
  const char* Bp = (const char*)(Bt + (long long)b * sB + (long long)bx * 128 * ldb + koff);

  int t = threadIdx.x, lane = t & 63;
  int wm = t >> 7, wn = (t >> 6) & 1;
  int rl = lane & 15, kq = lane >> 4;

  f32x4 acc[4][4];
#pragma unroll
  for (int i = 0; i < 4; ++i)
#pragma unroll
    for (int j = 0; j < 4; ++j) acc[i][j] = (f32x4){0.f, 0.f, 0.f, 0.f};

  int ldab = lda * 2, ldbb = ldb * 2;
  for (int k0 = 0; k0 < K; k0 += 64) {
    stage_tile(Ap + k0 * 2, ldab, smA, t);
    stage_tile(Bp + k0 * 2, ldbb, smB, t);
    __syncthreads();
    bf16x8 af[4][2], bf[4][2];
#pragma unroll
    for (int f = 0; f < 4; ++f)
#pragma unroll
      for (int ksl = 0; ksl < 2; ++ksl) {
        af[f][ksl] = read_frag(smA, wm * 64 + f * 16 + rl, ksl * 64 + kq * 16);
        bf[f][ksl] = read_frag(smB, wn * 64 + f * 16 + rl, ksl * 64 + kq * 16);
      }
#pragma unroll
    for (int fm = 0; fm < 4; ++fm)
#pragma unroll
      for (int fn = 0; fn < 4; ++fn) {
        acc[fm][fn] = MFMA16(af[fm][0], bf[fn][0], acc[fm][fn]);
        acc[fm][fn] = MFMA16(af[fm][1], bf[fn][1], acc[fm][fn]);
      }
    __syncthreads();
  }

#pragma unroll
  for (int fm = 0; fm < 4; ++fm)
#pragma unroll
    for (int fn = 0; fn < 4; ++fn)
#pragma unroll
      for (int j = 0; j < 4; ++j) {
        int row = by * 128 + wm * 64 + fm * 16 + kq * 4 + j;
        int col = bx * 128 + wn * 64 + fn * 16 + rl;
        if (MODE == 0) {
          ((u16*)Cv)[(long long)b * sC + (long long)row * ldc + col] = f2bf(acc[fm][fn][j]);
        } else {
          ((float*)Cv)[((long long)(ks * 8 + b)) * sC + (long long)row * ldc + col] =
              acc[fm][fn][j];
        }
      }
}

// ---------------------------------------------------------------------------
// gemm256: 256x256 tile, BK=32, 512 threads (8 waves 2Mx4N), quad-buffered
// 128 KB LDS, counted-vmcnt pipeline (T4), raw s_barrier (no __syncthreads ->
// no compiler vmcnt(0) drain), prefetch 2 K-steps ahead, setprio (T5).
// Sync proof: step t's loads issued at top of step t-2; wait vmcnt(4) at end
// of t-1 leaves only step t+1's 4 loads outstanding -> step t's retired; the
// barrier after each wave's own wait makes readiness collective. Buffer
// (t+2)&3 rewritten at top of t was last ds_read at step t-2, fully consumed
// before that step's end barrier (2 barriers separation). Never vmcnt(0) in
// steady state.
// 64B-row swizzle: c16 ^= (row>>1)&3 -> frag reads 2-way on banks (free);
// inverse applied on the global source (rule #21).
// ---------------------------------------------------------------------------
__device__ __forceinline__ void stage32(const char* __restrict__ g, int ldbytes,
                                        char* ldsbuf, int t, long long koffB) {
  int w = t >> 6, lane = t & 63;
#pragma unroll
  for (int i = 0; i < 2; ++i) {
    int c = w + i * 8;                 // 16 chunks of 1 KB = 16 KB tile
    int slot = c * 64 + lane;          // linear LDS 16B-slot
    int row = slot >> 2, c16 = slot & 3;
    int srcc = (c16 ^ ((row >> 1) & 3)) << 4;
    gload_lds16(g + (long long)row * ldbytes + koffB + srcc,
                ldsbuf + c * 1024);    // wave-uniform dest; HW adds lane*16
  }
}

__device__ __forceinline__ bf16x8 frag32(const char* ldsbuf, int r, int kq) {
  return *(const bf16x8*)(ldsbuf + r * 64 + ((kq ^ ((r >> 1) & 3)) << 4));
}

__global__ __launch_bounds__(512, 2) void gemm256(
    const u16* __restrict__ A, const u16* __restrict__ Bt, u16* __restrict__ C,
    int lda, int ldb, int ldc, int K) {
  extern __shared__ char lds[];   // 4 bufs x (A 16KB + B 16KB) = 128 KB

  unsigned nwg = gridDim.x * gridDim.y;
  unsigned orig = blockIdx.y * gridDim.x + blockIdx.x;
  unsigned cpx = nwg >> 3;
  unsigned swz = (orig & 7) * cpx + (orig >> 3);
  unsigned bx = swz % gridDim.x, by = swz / gridDim.x;

  const char* Ap = (const char*)(A + (long long)by * 256 * lda);
  const char* Bp = (const char*)(Bt + (long long)bx * 256 * ldb);
  int ldab = lda * 2, ldbb = ldb * 2;

  int t = threadIdx.x, lane = t & 63;
  int wid = t >> 6, wm = wid >> 2, wn = wid & 3;
  int rl = lane & 15, kq = lane >> 4;

  f32x4 acc[8][4];
#pragma unroll
  for (int i = 0; i < 8; ++i)
#pragma unroll
    for (int j = 0; j < 4; ++j) acc[i][j] = (f32x4){0.f, 0.f, 0.f, 0.f};

  // prologue: stage steps 0,1; wait own step-0 loads; collective barrier
  stage32(Ap, ldab, lds, t, 0);
  stage32(Bp, ldbb, lds + 16384, t, 0);
  stage32(Ap, ldab, lds + 32768, t, 64);
  stage32(Bp, ldbb, lds + 32768 + 16384, t, 64);
  asm volatile("s_waitcnt vmcnt(4)" ::: "memory");
  asm volatile("s_barrier" ::: "memory");

  int NT = K >> 5;
  for (int ts = 0; ts < NT; ++ts) {
    char* bufA = lds + (ts & 3) * 32768;
    char* bufB = bufA + 16384;
    if (ts + 2 < NT) {
      char* nb = lds + ((ts + 2) & 3) * 32768;
      stage32(Ap, ldab, nb, t, (long long)(ts + 2) << 6);
      stage32(Bp, ldbb, nb + 16384, t, (long long)(ts + 2) << 6);
    }
    bf16x8 af[8], bv[4];
#pragma unroll
    for (int fr = 0; fr < 8; ++fr) af[fr] = frag32(bufA, wm * 128 + fr * 16 + rl, kq);
#pragma unroll
    for (int fc = 0; fc < 4; ++fc) bv[fc] = frag32(bufB, wn * 64 + fc * 16 + rl, kq);
    __builtin_amdgcn_s_setprio(1);
#pragma unroll
    for (int fr = 0; fr < 8; ++fr)
#pragma unroll
      for (int fc = 0; fc < 4; ++fc)
        acc[fr][fc] = MFMA16(af[fr], bv[fc], acc[fr][fc]);
    __builtin_amdgcn_s_setprio(0);
    if (ts + 2 < NT)
      asm volatile("s_waitcnt vmcnt(4)" ::: "memory");  // keep next-next step in flight
    else
      asm volatile("s_waitcnt vmcnt(0)" ::: "memory");  // tail drain
    asm volatile("s_barrier" ::: "memory");
  }

  // Epilogue. C/D layout: col = lane&15, row = (lane>>4)*4 + reg  [m89]
#pragma unroll
  for (int fr = 0; fr < 8; ++fr)
#pragma unroll
    for (int fc = 0; fc < 4; ++fc)
#pragma unroll
      for (int j = 0; j < 4; ++j) {
        int row = by * 256 + wm * 128 + fr * 16 + kq * 4 + j;
        int col = bx * 256 + wn * 64 + fc * 16 + rl;
        C[(long long)row * ldc + col] = f2bf(acc[fr][fc][j]);
      }
}

// ---------------------------------------------------------------------------
// Merged: zq passthrough copy (output 0) + PV split-K combine (output 1).
// ---------------------------------------------------------------------------
__global__ void pv_combine_copy(const float* __restrict__ part, const float* __restrict__ xq,
                                const float* __restrict__ zq, float* __restrict__ out0,
                                float* __restrict__ out1) {
  int bid = blockIdx.x;
  if (bid < 2048) {
    int i = bid * 256 + threadIdx.x;
    ((float4*)out0)[i] = ((const float4*)zq)[i];
  } else {
    int i = (bid - 2048) * 256 + threadIdx.x;
    float4 s = ((const float4*)xq)[i];
#pragma unroll
    for (int k = 0; k < 4; ++k) {
      float4 p = ((const float4*)(part + (long long)k * 2097152))[i];
      s.x += p.x; s.y += p.y; s.z += p.z; s.w += p.w;
    }
    ((float4*)out1)[i] = s;
  }
}

// ---------------------------------------------------------------------------
// Pass 1: tile-structured row sums of exp(S), no max shift (scores ~N(0,1)
// by construction; f32 sumexp headroom ~30 orders).
// grid = (kt=32, qt=2, z=16: m=z>>1, hhalf=z&1), block = 256 (2x2 waves).
// ---------------------------------------------------------------------------
__global__ __launch_bounds__(256, 4) void attn_stats(
    const u16* __restrict__ qg, const u16* __restrict__ kg,
    float* __restrict__ lstP) {
  __shared__ __align__(16) char smQ[16384];
  __shared__ __align__(16) char smK[16384];
  int kt = blockIdx.x, qt = blockIdx.y;
  int m = blockIdx.z >> 1, hh = blockIdx.z & 1;
  int t = threadIdx.x, lane = t & 63;
  int wm = t >> 7, wn = (t >> 6) & 1;
  int rl = lane & 15, kq = lane >> 4;

  const char* qbase = (const char*)(qg + ((long long)(m * NQ_ + qt * 128)) * 1024);
  const char* kbase = (const char*)(kg + ((long long)(m * NKV_ + kt * 128)) * 1024);

  for (int hi = 0; hi < 8; ++hi) {
    int h = hh * 8 + hi;
    stage_tile(qbase + h * 128, 2048, smQ, t);
    stage_tile(kbase + h * 128, 2048, smK, t);
    __syncthreads();
    bf16x8 kf[4][2], qf[4][2];
#pragma unroll
    for (int f = 0; f < 4; ++f)
#pragma unroll
      for (int ksl = 0; ksl < 2; ++ksl) {
        kf[f][ksl] = read_frag(smK, wm * 64 + f * 16 + rl, ksl * 64 + kq * 16);
        qf[f][ksl] = read_frag(smQ, wn * 64 + f * 16 + rl, ksl * 64 + kq * 16);
      }
    float rs[4] = {0.f, 0.f, 0.f, 0.f};
#pragma unroll
    for (int fm = 0; fm < 4; ++fm)
#pragma unroll
      for (int fn = 0; fn < 4; ++fn) {
        f32x4 sc = (f32x4){0.f, 0.f, 0.f, 0.f};
        sc = MFMA16(kf[fm][0], qf[fn][0], sc);
        sc = MFMA16(kf[fm][1], qf[fn][1], sc);
        rs[fn] += (__expf(sc[0]) + __expf(sc[1])) + (__expf(sc[2]) + __expf(sc[3]));
      }
#pragma unroll
    for (int fn = 0; fn < 4; ++fn) {
      float v = rs[fn];
      v += __shfl_xor(v, 16);
      v += __shfl_xor(v, 32);
      if (lane < 16) {
        int q = qt * 128 + wn * 64 + fn * 16 + rl;
        lstP[(long long)(kt * 2 + wm) * 32768 + ((m * H_ + h) << 8) + q] = v;
      }
    }
    __syncthreads();
  }
}

// ---------------------------------------------------------------------------
// Merge the 64 (kt x wm) partial sums. Fixed order -> deterministic.
// ---------------------------------------------------------------------------
__global__ void stats_combine(const float* __restrict__ lp, float* __restrict__ lst) {
  int i = blockIdx.x * 256 + threadIdx.x;
  float s = 0.f;
#pragma unroll
  for (int k = 0; k < 64; ++k) s += lp[(long long)k * 32768 + i];
  lst[i] = s;
}

// ---------------------------------------------------------------------------
// Pass 2: Pbar[m,q,k] = sum_h (hw[h]/l[m,h,q]) * exp(s_h), bf16 out.
// grid = (kt=32, qt=2, m=8), block = 256.
// ---------------------------------------------------------------------------
__global__ __launch_bounds__(256, 2) void pbar_kernel(
    const u16* __restrict__ qg, const u16* __restrict__ kg,
    const float* __restrict__ lstat,
    const float* __restrict__ rawhw, u16* __restrict__ Pbar) {
  __shared__ __align__(16) char smQ[16384];
  __shared__ __align__(16) char smK[16384];
  __shared__ float scf[2048];
  int kt = blockIdx.x, qt = blockIdx.y, m = blockIdx.z;
  int q0 = qt * 128, k0 = kt * 128;
  int t = threadIdx.x, lane = t & 63;
  int wm = t >> 7, wn = (t >> 6) & 1;
  int rl = lane & 15, kq = lane >> 4;

  float hm = -1e30f;
  for (int i = 0; i < H_; ++i) hm = fmaxf(hm, rawhw[i]);
  float hs = 0.f, hw[H_];
  for (int i = 0; i < H_; ++i) { hw[i] = __expf(rawhw[i] - hm); hs += hw[i]; }
  float hinv = 1.f / hs;
  for (int idx = t; idx < 2048; idx += 256) {
    int h = idx >> 7, r = idx & 127;
    scf[idx] = hw[h] * hinv / lstat[((m * H_ + h) << 8) + q0 + r];
  }

  f32x4 pacc[4][4];
#pragma unroll
  for (int i = 0; i < 4; ++i)
#pragma unroll
    for (int j = 0; j < 4; ++j) pacc[i][j] = (f32x4){0.f, 0.f, 0.f, 0.f};

  const char* qbase = (const char*)(qg + ((long long)(m * NQ_ + q0)) * 1024);
  const char* kbase = (const char*)(kg + ((long long)(m * NKV_ + k0)) * 1024);

  for (int h = 0; h < H_; ++h) {
    stage_tile(qbase + h * 128, 2048, smQ, t);
    stage_tile(kbase + h * 128, 2048, smK, t);
    __syncthreads();  // also orders the scf writes above (first iter)
    bf16x8 af[4][2], bfr[4][2];
#pragma unroll
    for (int f = 0; f < 4; ++f)
#pragma unroll
      for (int ksl = 0; ksl < 2; ++ksl) {
        af[f][ksl] = read_frag(smQ, wm * 64 + f * 16 + rl, ksl * 64 + kq * 16);
        bfr[f][ksl] = read_frag(smK, wn * 64 + f * 16 + rl, ksl * 64 + kq * 16);
      }
#pragma unroll
    for (int fm = 0; fm < 4; ++fm) {
      int rbase = wm * 64 + fm * 16 + kq * 4;
      float cf0 = scf[(h << 7) + rbase + 0];
      float cf1 = scf[(h << 7) + rbase + 1];
      float cf2 = scf[(h << 7) + rbase + 2];
      float cf3 = scf[(h << 7) + rbase + 3];
#pragma unroll
      for (int fn = 0; fn < 4; ++fn) {
        f32x4 sc = (f32x4){0.f, 0.f, 0.f, 0.f};
        sc = MFMA16(af[fm][0], bfr[fn][0], sc);
        sc = MFMA16(af[fm][1], bfr[fn][1], sc);
        pacc[fm][fn][0] += cf0 * __expf(sc[0]);
        pacc[fm][fn][1] += cf1 * __expf(sc[1]);
        pacc[fm][fn][2] += cf2 * __expf(sc[2]);
        pacc[fm][fn][3] += cf3 * __expf(sc[3]);
      }
    }
    __syncthreads();
  }
#pragma unroll
  for (int fm = 0; fm < 4; ++fm)
#pragma unroll
    for (int fn = 0; fn < 4; ++fn)
#pragma unroll
      for (int j = 0; j < 4; ++j) {
        int row = q0 + wm * 64 + fm * 16 + kq * 4 + j;
        int col = k0 + wn * 64 + fn * 16 + rl;
        Pbar[(((long long)m * NQ_ + row) << 12) + col] = f2bf(pacc[fm][fn][j]);
      }
}

// ---------------------------------------------------------------------------
// Merged prep: f32->bf16 converts (zq, zkv) + transposed converts (Wq, Wk,
// xkv). Block-granular branching; one dispatch instead of four.
//   [0, 17408): cvt8 (zq first 1024 blocks, then zkv)
//   [17408, 17664): Wq 64x64 transpose tiles (alpha = 0.125, folds SCALE)
//   [17664, 17920): Wk tiles
//   [17920, 26112): xkv tiles (8 batches x 64 r-tiles x 16 c-tiles)
// ---------------------------------------------------------------------------
__global__ void prep_kernel(const float* __restrict__ zq, u16* __restrict__ zqb,
                            const float* __restrict__ zkv, u16* __restrict__ zkvb,
                            const float* __restrict__ Wq, u16* __restrict__ WqT,
                            const float* __restrict__ Wk, u16* __restrict__ WkT,
                            const float* __restrict__ xkv, u16* __restrict__ xkvT) {
  __shared__ float tile[64][65];
  int bid = blockIdx.x;
  if (bid < 17408) {
    const float* in; u16* out; long long i;
    if (bid < 1024) { in = zq; out = zqb; i = (long long)bid * 256 + threadIdx.x; }
    else { in = zkv; out = zkvb; i = (long long)(bid - 1024) * 256 + threadIdx.x; }
    const float4* p = (const float4*)in + i * 2;
    float4 a = p[0], b = p[1];
    u16x8 v;
    v[0] = f2bf(a.x); v[1] = f2bf(a.y); v[2] = f2bf(a.z); v[3] = f2bf(a.w);
    v[4] = f2bf(b.x); v[5] = f2bf(b.y); v[6] = f2bf(b.z); v[7] = f2bf(b.w);
    *(u16x8*)(out + i * 8) = v;
    return;
  }
  const float* in; u16* out; int R, C; float alpha; int r0, c0;
  if (bid < 17664) {
    int id = bid - 17408;
    in = Wq; out = WqT; R = 1024; C = 1024; alpha = 0.125f;
    r0 = (id & 15) * 64; c0 = (id >> 4) * 64;
  } else if (bid < 17920) {
    int id = bid - 17664;
    in = Wk; out = WkT; R = 1024; C = 1024; alpha = 1.0f;
    r0 = (id & 15) * 64; c0 = (id >> 4) * 64;
  } else {
    int id = bid - 17920;
    int bz = id >> 10, rem = id & 1023;
    in = xkv + (long long)bz * NKV_ * E_;
    out = xkvT + (long long)bz * NKV_ * E_;
    R = NKV_; C = E_; alpha = 1.0f;
    r0 = (rem & 63) * 64; c0 = (rem >> 6) * 64;
  }
  int t = threadIdx.x;
  int rr = t >> 4, c4 = t & 15;
#pragma unroll
  for (int i = 0; i < 4; ++i) {
    float4 v = *(const float4*)(in + (long long)(r0 + rr + i * 16) * C + c0 + c4 * 4);
    float* d = &tile[rr + i * 16][c4 * 4];
    d[0] = v.x; d[1] = v.y; d[2] = v.z; d[3] = v.w;
  }
  __syncthreads();
  int cc = t >> 3, r8 = t & 7;
#pragma unroll
  for (int i = 0; i < 2; ++i) {
    int c = cc + i * 32;
    u16x8 v;
#pragma unroll
    for (int j = 0; j < 8; ++j) v[j] = f2bf(alpha * tile[r8 * 8 + j][c]);
    *(u16x8*)(out + (long long)(c0 + c) * R + r0 + r8 * 8) = v;
  }
}

// ---------------------------------------------------------------------------
extern "C" void kernel_launch(void* const* d_in, const int* in_sizes, int n_in,
                              void* d_out, int out_size, void* d_ws, size_t ws_size,
                              hipStream_t stream) {
  const float* zq  = (const float*)d_in[0];
  const float* zkv = (const float*)d_in[1];
  const float* xq  = (const float*)d_in[2];
  const float* xkv = (const float*)d_in[3];
  const float* Wq  = (const float*)d_in[4];
  const float* Wk  = (const float*)d_in[5];
  const float* rhw = (const float*)d_in[6];
  float* out = (float*)d_out;

  // Workspace layout (bytes). Total need: ~172 MB.
  char* ws = (char*)d_ws;
  u16* WqT  = (u16*)(ws);                      //  2 MB  [1024][1024] (x0.125 folded)
  u16* WkT  = (u16*)(ws + (2ull << 20));       //  2 MB
  u16* zqb  = (u16*)(ws + (4ull << 20));       //  4 MB  [2048][1024]
  u16* qb   = (u16*)(ws + (8ull << 20));       //  4 MB  [2048][1024] (pre-scaled)
  u16* kb   = (u16*)(ws + (12ull << 20));      // 64 MB  [32768][1024]
  u16* xkvT = (u16*)(ws + (76ull << 20));      // 64 MB  [8][1024][4096]
  char* zr  = ws + (140ull << 20);             // 64 MB region, dual-use:
  u16* zkvb = (u16*)zr;                        //   zkv bf16 (dead after Kproj)
  u16* Pbar = (u16*)zr;                        //   then Pbar [8][256][4096] (16 MB)
  float* lst  = (float*)(zr + (18ull << 20));  //   final sumexp (128 KB)
  float* lstP = (float*)(zr + (20ull << 20));  //   partial sumexp [64][32768] (8 MB)
  float* pvP  = (float*)(zr + (28ull << 20));  //   PV split-K partials (32 MB)

  // allow 128 KB dynamic LDS for gemm256 (idempotent, non-stream call)
  (void)hipFuncSetAttribute((const void*)gemm256,
                            hipFuncAttributeMaxDynamicSharedMemorySize, 131072);

  // 1. all dtype converts in one dispatch
  prep_kernel<<<26112, 256, 0, stream>>>(zq, zqb, zkv, zkvb, Wq, WqT, Wk, WkT, xkv, xkvT);

  // 2. projections: Qproj on the 128^2 kernel; Kproj on the 256^2
  //    counted-vmcnt pipeline (grid 4x128 = 512 blocks, 512 thr, 128 KB LDS)
  gemm_nt<0><<<dim3(8, 16, 1), 256, 0, stream>>>(zqb, WqT, qb,
                                                 1024, 1024, 1024, 1024, 0, 0, 0);
  gemm256<<<dim3(4, 128, 1), 512, 131072, stream>>>(zkvb, WkT, kb, 1024, 1024, 1024, 1024);

  // 3. softmax denominators
  attn_stats<<<dim3(32, 2, 16), 256, 0, stream>>>(qb, kb, lstP);
  stats_combine<<<128, 256, 0, stream>>>(lstP, lst);

  // 4. head-collapsed probabilities
  pbar_kernel<<<dim3(32, 2, 8), 256, 0, stream>>>(qb, kb, lst, rhw, Pbar);

  // 5. PV split-K x4 -> f32 partials, then combine with residual + zq copy
  gemm_nt<2><<<dim3(8, 2, 32), 256, 0, stream>>>(Pbar, xkvT, pvP,
                                                 4096, 4096, 1024, 1024,
                                                 256LL * 4096, 1024LL * 4096,
                                                 256LL * 1024);
  pv_combine_copy<<<4096, 256, 0, stream>>>(pvP, xq, zq, out,
                                            out + (long long)MB_ * NQ_ * E_);
}